// Round 9
// baseline (478.798 us; speedup 1.0000x reference)
//
#include <hip/hip_runtime.h>
#include <cstdint>
#include <cstddef>

#define T_DATA 20000
#define E_NO 2000
#define I_NO 500
#define SUB_NO 16
#define HID 256
#define T_SYN 200
#define T_ENC 80
#define W_IN 159   // 2*T_ENC-1

typedef __attribute__((ext_vector_type(8))) __bf16 bf16x8;
typedef __attribute__((ext_vector_type(8))) short short8;
typedef __attribute__((ext_vector_type(4))) float floatx4;
typedef __attribute__((ext_vector_type(4))) unsigned int uint4v;
typedef __attribute__((ext_vector_type(2))) unsigned int uint2v;

__device__ __forceinline__ float bf2f(unsigned short u) {
    union { unsigned int i; float f; } v; v.i = ((unsigned int)u) << 16; return v.f;
}
__device__ __forceinline__ unsigned short f2bf(float f) {
    union { float f; unsigned int i; } v; v.f = f;
    unsigned int r = v.i + 0x7FFFu + ((v.i >> 16) & 1u);
    return (unsigned short)(r >> 16);
}
__device__ __forceinline__ float inload(const void* p, int i, int isbf) {
    return isbf ? bf2f(((const unsigned short*)p)[i]) : ((const float*)p)[i];
}

// per-block dtype detection: scan first 1024 u32 words of S_e (4 KB, L2-hot).
__device__ __forceinline__ int detect_bf(const void* Se, int* sfl) {
    if (threadIdx.x == 0) *sfl = 0;
    __syncthreads();
    const unsigned int* w = (const unsigned int*)Se;
    int la = 0;
    #pragma unroll
    for (int i = 0; i < 4; i++)
        la |= (w[i * 256 + threadIdx.x] & 0xFFFFu) ? 1 : 0;
    if (la) atomicOr(sfl, 1);
    __syncthreads();
    return *sfl;
}

// ---------------- ws layout (bytes, all 16B aligned) ----------------
// W1..W4 stored in MFMA-FRAGMENT-PACKED order (see k_spikes): the
// B-fragment load for (tile,ks) is base + lane*16B -> fully coalesced.
#define OFF_KERE   16u        // 16*200 f32
#define OFF_KERI   12816u
#define OFF_SHE    25616u     // 2000 u8 (subunit*8 per e-synapse)
#define OFF_SHI    33616u     // 500 u8
#define OFF_W1H    35616u     // 40960 bf16 packed (16 tiles x 5 ks x 64 lanes x 8)
#define OFF_W1L    117536u
#define OFF_W2H    199456u    // 65536 bf16 packed (16 x 8 x 64 x 8)
#define OFF_W2L    330528u
#define OFF_W3H    461600u
#define OFF_W3L    592672u
#define OFF_W4H    723744u    // 4096 bf16 packed (8 ks x 64 lanes x 8), n zero-padded
#define OFF_W4L    731936u
#define OFF_INE    740128u    // 20000*16 u8
#define OFF_INI    1060128u
#define OFF_ALO    1380128u   // f32-fallback Alo scratch: 313 blocks x 32768 B

// ================= kernel 1: tiny tables (ker + subunit maps) =================
__global__ void k_tables(const void* Se, const void* Ksyn, const void* tau_syn, const void* dly,
                         const void* Ce, const void* Ci,
                         float* ker_e, float* ker_i, unsigned char* sh_e, unsigned char* sh_i) {
    __shared__ int sfl;
    int f = detect_bf(Se, &sfl);
    int id = blockIdx.x * 256 + threadIdx.x;
    if (id < 6400) {
        int c = id < 3200 ? 0 : 1;
        int q = id - c * 3200;
        int s = q / 200, j = q - s * 200;
        float d = expf(inload(dly, s * 2 + c, f));
        float tt = fmaxf((float)j - d, 0.0f);
        float acc = 0.f;
        #pragma unroll
        for (int b = 0; b < 3; b++) {
            float tau = expf(inload(tau_syn, b * 3 + c, f));
            float x = tt / tau;
            acc += x * expf(-x) * inload(Ksyn, (s * 3 + b) * 3 + c, f);
        }
        (c == 0 ? ker_e : ker_i)[s * 200 + j] = acc;
    } else if (id < 8400) {
        int e = id - 6400;
        int a = 0;
        for (int s = 0; s < 16; s++) if (inload(Ce, s * E_NO + e, f) > 0.5f) a = s;
        sh_e[e] = (unsigned char)(a * 8);
    } else if (id < 8900) {
        int e = id - 8400;
        int a = 0;
        for (int s = 0; s < 16; s++) if (inload(Ci, s * I_NO + e, f) > 0.5f) a = s;
        sh_i[e] = (unsigned char)(a * 8);
    }
}

// ============ kernel 2: spike -> subunit counts (u8), BRANCHLESS ============
// Also absorbs W1-W4 hi/lo conversion into FRAGMENT-PACKED layout.
__device__ __forceinline__ void acc_slot(unsigned int b, unsigned int sh,
                                         unsigned long long& lo, unsigned long long& hi) {
    unsigned int up = sh >> 6;            // 1 if subunit >= 8
    unsigned int s6 = sh & 63;
    lo += (unsigned long long)(b & (up ^ 1u)) << s6;
    hi += (unsigned long long)(b & up) << s6;
}

__global__ void __launch_bounds__(256) k_spikes(const void* Se, const void* Si,
                         const unsigned char* sh_e, const unsigned char* sh_i,
                         const void* W1, const void* W2, const void* W3, const void* W4,
                         unsigned char* in_e, unsigned char* in_i,
                         unsigned short* W1h, unsigned short* W1l,
                         unsigned short* W2h, unsigned short* W2l,
                         unsigned short* W3h, unsigned short* W3l,
                         unsigned short* W4h, unsigned short* W4l) {
    __shared__ int sfl;
    __shared__ __align__(8) unsigned char she[E_NO];
    __shared__ __align__(8) unsigned char shi[I_NO];
    for (int i = threadIdx.x; i < E_NO / 4; i += 256)
        ((unsigned int*)she)[i] = ((const unsigned int*)sh_e)[i];
    for (int i = threadIdx.x; i < I_NO / 4; i += 256)
        ((unsigned int*)shi)[i] = ((const unsigned int*)sh_i)[i];
    int f = detect_bf(Se, &sfl);   // its syncthreads also covers table staging
    int lane = threadIdx.x & 63;
    int wave = threadIdx.x >> 6;
    int t = blockIdx.x * 4 + wave;
    unsigned long long e0 = 0, e1 = 0, i0 = 0, i1 = 0;
    if (f) {
        const uint4v* re = (const uint4v*)((const unsigned short*)Se + (size_t)t * E_NO);
        #pragma unroll
        for (int it = 0; it < 4; it++) {
            int c = it * 64 + lane;
            if (c < 250) {
                uint4v v = re[c];
                unsigned long long q = *(const unsigned long long*)&she[c * 8];
                #pragma unroll
                for (int w = 0; w < 4; w++) {
                    unsigned int x = v[w];
                    acc_slot((x >> 7) & 1u,  (unsigned int)(q >> (16 * w)) & 0xFFu, e0, e1);
                    acc_slot((x >> 23) & 1u, (unsigned int)(q >> (16 * w + 8)) & 0xFFu, e0, e1);
                }
            }
        }
        const uint2v* ri = (const uint2v*)((const unsigned short*)Si + (size_t)t * I_NO);
        #pragma unroll
        for (int it = 0; it < 2; it++) {
            int c = it * 64 + lane;
            if (c < 125) {
                uint2v v = ri[c];
                unsigned int q = *(const unsigned int*)&shi[c * 4];
                #pragma unroll
                for (int w = 0; w < 2; w++) {
                    unsigned int x = v[w];
                    acc_slot((x >> 7) & 1u,  (q >> (16 * w)) & 0xFFu, i0, i1);
                    acc_slot((x >> 23) & 1u, (q >> (16 * w + 8)) & 0xFFu, i0, i1);
                }
            }
        }
    } else {
        const uint4v* re = (const uint4v*)((const float*)Se + (size_t)t * E_NO);
        #pragma unroll
        for (int it = 0; it < 8; it++) {
            int c = it * 64 + lane;
            if (c < 500) {
                uint4v v = re[c];
                unsigned int q = *(const unsigned int*)&she[c * 4];
                #pragma unroll
                for (int w = 0; w < 4; w++)
                    acc_slot((v[w] >> 23) & 1u, (q >> (8 * w)) & 0xFFu, e0, e1);
            }
        }
        const uint2v* ri = (const uint2v*)((const float*)Si + (size_t)t * I_NO);
        #pragma unroll
        for (int it = 0; it < 4; it++) {
            int c = it * 64 + lane;
            if (c < 250) {
                uint2v v = ri[c];
                unsigned int q = *(const unsigned short*)&shi[c * 2];
                #pragma unroll
                for (int w = 0; w < 2; w++)
                    acc_slot((v[w] >> 23) & 1u, (q >> (8 * w)) & 0xFFu, i0, i1);
            }
        }
    }
    for (int off = 32; off; off >>= 1) {
        e0 += __shfl_xor(e0, off);
        e1 += __shfl_xor(e1, off);
        i0 += __shfl_xor(i0, off);
        i1 += __shfl_xor(i1, off);
    }
    if (lane < 16) {
        unsigned long long a = (lane < 8) ? e0 : e1;
        in_e[(size_t)t * 16 + lane] = (unsigned char)((a >> ((lane & 7) * 8)) & 0xFF);
    } else if (lane < 32) {
        int s = lane - 16;
        unsigned long long a = (s < 8) ? i0 : i1;
        in_i[(size_t)t * 16 + s] = (unsigned char)((a >> ((s & 7) * 8)) & 0xFF);
    }
    // ---- folded weight conversion into packed layout (688*256 = 176128) ----
    if (blockIdx.x < 688) {
        int q = blockIdx.x * 256 + threadIdx.x;   // packed linear index
        if (q < 40960) {                          // W1: KS=5, pad k 159->160
            int j = q & 7, l = (q >> 3) & 63, r = q >> 9;   // r in [0,80)
            int ks = r % 5, tile = r / 5;
            int n = tile * 16 + (l & 15);
            int k = ks * 32 + (l >> 4) * 8 + j;
            float v = (k < W_IN) ? inload(W1, n * W_IN + k, f) : 0.f;
            unsigned short hi = f2bf(v);
            W1h[q] = hi;
            W1l[q] = f2bf(v - bf2f(hi));
        } else if (q < 106496) {                  // W2: KS=8
            int p = q - 40960;
            int j = p & 7, l = (p >> 3) & 63, r = p >> 9;   // r in [0,128)
            int ks = r & 7, tile = r >> 3;
            int n = tile * 16 + (l & 15);
            int k = ks * 32 + (l >> 4) * 8 + j;
            float v = inload(W2, n * 256 + k, f);
            unsigned short hi = f2bf(v);
            W2h[p] = hi;
            W2l[p] = f2bf(v - bf2f(hi));
        } else if (q < 172032) {                  // W3: KS=8
            int p = q - 106496;
            int j = p & 7, l = (p >> 3) & 63, r = p >> 9;
            int ks = r & 7, tile = r >> 3;
            int n = tile * 16 + (l & 15);
            int k = ks * 32 + (l >> 4) * 8 + j;
            float v = inload(W3, n * 256 + k, f);
            unsigned short hi = f2bf(v);
            W3h[p] = hi;
            W3l[p] = f2bf(v - bf2f(hi));
        } else {                                  // W4: 8 ks, n zero-padded to 16
            int p = q - 172032;                   // [0,4096)
            int j = p & 7, l = (p >> 3) & 63, ks = p >> 9;
            int lm = l & 15, quad = l >> 4;
            float v = 0.f;
            if (lm < 15) v = inload(W4, lm * 256 + ks * 32 + quad * 8 + j, f);
            unsigned short hi = f2bf(v);
            W4h[p] = hi;
            W4l[p] = f2bf(v - bf2f(hi));
        }
    }
}

// ============ kernel 3: fused conv + MLP, restructured conv ============
// MLP identical to r8 (proven 355 us). Conv restructured: e/i split across
// threads (arr = tid>>7), 8 rows/thread, windows read DIRECTLY from global
// (in_e/in_i are L2-resident; lanes s=0..15 hit 16 consecutive bytes ->
// coalesced; deep vmcnt queue pipelines), kernel coefficients broadcast from
// LDS. unroll 8 register-renames the window rotation. Cuts conv LDS instrs
// ~4x and rotation VALU ~100%. LDS: kernels (25.7K) UNION Ahi (32K) + Sc
// [2][64][16] (8K) ~= 41 KB. f32-fallback Alo lives in global ws scratch.
template<bool BF>
__device__ __forceinline__ void mlp_body(
    const void* V,
    const unsigned short* W1h, const unsigned short* W1l, const void* b1, const void* a1p,
    const unsigned short* W2h, const unsigned short* W2l, const void* b2, const void* a2p,
    const unsigned short* W3h, const unsigned short* W3l, const void* b3, const void* a3p,
    const unsigned short* W4h, const unsigned short* W4l, const void* b4,
    const void* encb, const float* Sc, void* out,
    unsigned short* Ahi, unsigned short* AloG,
    const bf16x8 (&Bh1)[5][4])
{
    int tid = threadIdx.x;
    int lane = tid & 63, wave = tid >> 6;
    int lm = lane & 15, quad = lane >> 4;
    int t0 = blockIdx.x * 64;

    auto ld = [&](const void* p, int i) -> float {
        return BF ? bf2f(((const unsigned short*)p)[i]) : ((const float*)p)[i];
    };
    // packed fragment offsets (elements)
    auto boff1 = [&](int ks, int nt) { return (size_t)((((wave * 4 + nt) * 5 + ks) * 64 + lane) << 3); };
    auto boff  = [&](int ks, int nt) { return (size_t)((((wave * 4 + nt) * 8 + ks) * 64 + lane) << 3); };

    // stage layer-1 A: 64 rows x 160 cols, XOR kgroup swizzle (5-bit row mask)
    for (int idx = tid; idx < 64 * 160; idx += 256) {
        int m = idx / 160, k = idx - m * 160;
        int tg = t0 + m + k - (T_ENC - 1);
        float v = 0.f;
        if (k < W_IN && tg >= 0 && tg < T_DATA) v = ld(V, tg);
        unsigned short hi = f2bf(v);
        int col = (((k >> 3) ^ (m & 31)) << 3) | (k & 7);
        Ahi[m * 256 + col] = hi;
        if (!BF) AloG[m * 256 + col] = f2bf(v - bf2f(hi));
    }
    __syncthreads();

    floatx4 acc[4][4];   // [mt][nt] -> AGPRs
    auto aoff = [&](int mt, int ks) {
        int arow = mt * 16 + lm;
        return arow * 256 + ((((ks << 2) | quad) ^ (arow & 31)) << 3);
    };

    auto epi = [&](const void* bias, float alpha) {
        __syncthreads();
        #pragma unroll
        for (int mt = 0; mt < 4; mt++) {
            #pragma unroll
            for (int nt = 0; nt < 4; nt++) {
                int cn = wave * 64 + nt * 16 + lm;
                float bb = ld(bias, cn);
                #pragma unroll
                for (int j = 0; j < 4; j++) {
                    int row = mt * 16 + quad * 4 + j;
                    float h = acc[mt][nt][j] + bb;
                    h = (h >= 0.f) ? h : alpha * h;
                    unsigned short hi = f2bf(h);
                    int col = (((cn >> 3) ^ (row & 31)) << 3) | (cn & 7);
                    Ahi[row * 256 + col] = hi;
                    if (!BF) AloG[row * 256 + col] = f2bf(h - bf2f(hi));
                }
            }
        }
        __syncthreads();
    };

    floatx4 z = {0.f, 0.f, 0.f, 0.f};

    if (BF) {
        // ================= pipelined bf16 path (r8 verbatim) =================
        bf16x8 Bc[4][4], Bn[4][4];
        // ---- layer 1: K=160 (5 ks), B preloaded in Bh1 ----
        #pragma unroll
        for (int mt = 0; mt < 4; mt++)
            #pragma unroll
            for (int nt = 0; nt < 4; nt++) acc[mt][nt] = z;
        #pragma unroll
        for (int ks = 0; ks < 5; ks++) {
            bf16x8 a[4];
            #pragma unroll
            for (int mt = 0; mt < 4; mt++) a[mt] = *(const bf16x8*)&Ahi[aoff(mt, ks)];
            #pragma unroll
            for (int nt = 0; nt < 4; nt++)
                #pragma unroll
                for (int mt = 0; mt < 4; mt++)
                    acc[mt][nt] = __builtin_amdgcn_mfma_f32_16x16x32_bf16(a[mt], Bh1[ks][nt], acc[mt][nt], 0, 0, 0);
        }
        // prefetch W2 chunk0
        #pragma unroll
        for (int c = 0; c < 4; c++)
            #pragma unroll
            for (int nt = 0; nt < 4; nt++)
                Bc[c][nt] = *(const bf16x8*)(W2h + boff(c, nt));
        epi(b1, ld(a1p, 0));

        // ---- layer 2 ----
        #pragma unroll
        for (int mt = 0; mt < 4; mt++)
            #pragma unroll
            for (int nt = 0; nt < 4; nt++) acc[mt][nt] = z;
        #pragma unroll
        for (int c = 0; c < 4; c++)
            #pragma unroll
            for (int nt = 0; nt < 4; nt++)
                Bn[c][nt] = *(const bf16x8*)(W2h + boff(4 + c, nt));
        #pragma unroll
        for (int c = 0; c < 4; c++) {
            bf16x8 a[4];
            #pragma unroll
            for (int mt = 0; mt < 4; mt++) a[mt] = *(const bf16x8*)&Ahi[aoff(mt, c)];
            #pragma unroll
            for (int nt = 0; nt < 4; nt++)
                #pragma unroll
                for (int mt = 0; mt < 4; mt++)
                    acc[mt][nt] = __builtin_amdgcn_mfma_f32_16x16x32_bf16(a[mt], Bc[c][nt], acc[mt][nt], 0, 0, 0);
        }
        #pragma unroll
        for (int c = 0; c < 4; c++)
            #pragma unroll
            for (int nt = 0; nt < 4; nt++)
                Bc[c][nt] = *(const bf16x8*)(W3h + boff(c, nt));
        #pragma unroll
        for (int c = 0; c < 4; c++) {
            bf16x8 a[4];
            #pragma unroll
            for (int mt = 0; mt < 4; mt++) a[mt] = *(const bf16x8*)&Ahi[aoff(mt, 4 + c)];
            #pragma unroll
            for (int nt = 0; nt < 4; nt++)
                #pragma unroll
                for (int mt = 0; mt < 4; mt++)
                    acc[mt][nt] = __builtin_amdgcn_mfma_f32_16x16x32_bf16(a[mt], Bn[c][nt], acc[mt][nt], 0, 0, 0);
        }
        epi(b2, ld(a2p, 0));

        // ---- layer 3 ----
        #pragma unroll
        for (int mt = 0; mt < 4; mt++)
            #pragma unroll
            for (int nt = 0; nt < 4; nt++) acc[mt][nt] = z;
        #pragma unroll
        for (int c = 0; c < 4; c++)
            #pragma unroll
            for (int nt = 0; nt < 4; nt++)
                Bn[c][nt] = *(const bf16x8*)(W3h + boff(4 + c, nt));
        #pragma unroll
        for (int c = 0; c < 4; c++) {
            bf16x8 a[4];
            #pragma unroll
            for (int mt = 0; mt < 4; mt++) a[mt] = *(const bf16x8*)&Ahi[aoff(mt, c)];
            #pragma unroll
            for (int nt = 0; nt < 4; nt++)
                #pragma unroll
                for (int mt = 0; mt < 4; mt++)
                    acc[mt][nt] = __builtin_amdgcn_mfma_f32_16x16x32_bf16(a[mt], Bc[c][nt], acc[mt][nt], 0, 0, 0);
        }
        bf16x8 w4[8];
        #pragma unroll
        for (int ks = 0; ks < 8; ks++)
            w4[ks] = *(const bf16x8*)(W4h + (size_t)((ks * 64 + lane) << 3));
        #pragma unroll
        for (int c = 0; c < 4; c++) {
            bf16x8 a[4];
            #pragma unroll
            for (int mt = 0; mt < 4; mt++) a[mt] = *(const bf16x8*)&Ahi[aoff(mt, 4 + c)];
            #pragma unroll
            for (int nt = 0; nt < 4; nt++)
                #pragma unroll
                for (int mt = 0; mt < 4; mt++)
                    acc[mt][nt] = __builtin_amdgcn_mfma_f32_16x16x32_bf16(a[mt], Bn[c][nt], acc[mt][nt], 0, 0, 0);
        }
        epi(b3, ld(a3p, 0));

        // ---- layer 4: preloaded w4, wave takes M-tile mt=wave ----
        {
            int mt = wave;
            floatx4 a4 = z;
            #pragma unroll
            for (int ks = 0; ks < 8; ks++) {
                bf16x8 ah = *(const bf16x8*)&Ahi[aoff(mt, ks)];
                a4 = __builtin_amdgcn_mfma_f32_16x16x32_bf16(ah, w4[ks], a4, 0, 0, 0);
            }
            if (lm < 15) {
                float bb = ld(b4, lm) + ld(encb, lm);
                #pragma unroll
                for (int j = 0; j < 4; j++) {
                    int row = mt * 16 + quad * 4 + j;
                    int t = t0 + row;
                    if (t < T_DATA) {
                        float x = a4[j] + bb + Sc[row * 16 + lm + 1] + Sc[1024 + row * 16 + lm + 1];
                        x = fminf(fmaxf(x, -40.f), 40.f);
                        float sg = 1.f / (1.f + expf(-x));
                        ((unsigned short*)out)[(size_t)t * 15 + lm] = f2bf(sg);
                    }
                }
            }
        }
    } else {
        // ================= f32 fallback (cold path; Alo in global scratch) =====
        {
            #pragma unroll
            for (int mt = 0; mt < 4; mt++)
                #pragma unroll
                for (int nt = 0; nt < 4; nt++) acc[mt][nt] = z;
            #pragma unroll
            for (int ks = 0; ks < 5; ks++) {
                bf16x8 ah[4], al[4];
                #pragma unroll
                for (int mt = 0; mt < 4; mt++) {
                    ah[mt] = *(const bf16x8*)&Ahi[aoff(mt, ks)];
                    al[mt] = *(const bf16x8*)(AloG + aoff(mt, ks));
                }
                #pragma unroll
                for (int nt = 0; nt < 4; nt++) {
                    bf16x8 bh = Bh1[ks][nt];
                    bf16x8 bl = *(const bf16x8*)(W1l + boff1(ks, nt));
                    #pragma unroll
                    for (int mt = 0; mt < 4; mt++) {
                        acc[mt][nt] = __builtin_amdgcn_mfma_f32_16x16x32_bf16(ah[mt], bh, acc[mt][nt], 0, 0, 0);
                        acc[mt][nt] = __builtin_amdgcn_mfma_f32_16x16x32_bf16(al[mt], bh, acc[mt][nt], 0, 0, 0);
                        acc[mt][nt] = __builtin_amdgcn_mfma_f32_16x16x32_bf16(ah[mt], bl, acc[mt][nt], 0, 0, 0);
                    }
                }
            }
            epi(b1, ld(a1p, 0));
        }
        const unsigned short* Whs[2] = {W2h, W3h};
        const unsigned short* Wls[2] = {W2l, W3l};
        const void* bs[2] = {b2, b3};
        const void* as_[2] = {a2p, a3p};
        for (int l = 0; l < 2; l++) {
            #pragma unroll
            for (int mt = 0; mt < 4; mt++)
                #pragma unroll
                for (int nt = 0; nt < 4; nt++) acc[mt][nt] = z;
            const unsigned short* Wh = Whs[l];
            const unsigned short* Wl = Wls[l];
            #pragma unroll
            for (int ks = 0; ks < 8; ks++) {
                bf16x8 ah[4], al[4];
                #pragma unroll
                for (int mt = 0; mt < 4; mt++) {
                    ah[mt] = *(const bf16x8*)&Ahi[aoff(mt, ks)];
                    al[mt] = *(const bf16x8*)(AloG + aoff(mt, ks));
                }
                #pragma unroll
                for (int nt = 0; nt < 4; nt++) {
                    bf16x8 bh = *(const bf16x8*)(Wh + boff(ks, nt));
                    bf16x8 bl = *(const bf16x8*)(Wl + boff(ks, nt));
                    #pragma unroll
                    for (int mt = 0; mt < 4; mt++) {
                        acc[mt][nt] = __builtin_amdgcn_mfma_f32_16x16x32_bf16(ah[mt], bh, acc[mt][nt], 0, 0, 0);
                        acc[mt][nt] = __builtin_amdgcn_mfma_f32_16x16x32_bf16(al[mt], bh, acc[mt][nt], 0, 0, 0);
                        acc[mt][nt] = __builtin_amdgcn_mfma_f32_16x16x32_bf16(ah[mt], bl, acc[mt][nt], 0, 0, 0);
                    }
                }
            }
            epi(bs[l], ld(as_[l], 0));
        }
        {
            int mt = wave;
            floatx4 a4 = z;
            #pragma unroll
            for (int ks = 0; ks < 8; ks++) {
                bf16x8 ah = *(const bf16x8*)&Ahi[aoff(mt, ks)];
                bf16x8 bh = *(const bf16x8*)(W4h + (size_t)((ks * 64 + lane) << 3));
                a4 = __builtin_amdgcn_mfma_f32_16x16x32_bf16(ah, bh, a4, 0, 0, 0);
                bf16x8 al = *(const bf16x8*)(AloG + aoff(mt, ks));
                bf16x8 bl = *(const bf16x8*)(W4l + (size_t)((ks * 64 + lane) << 3));
                a4 = __builtin_amdgcn_mfma_f32_16x16x32_bf16(al, bh, a4, 0, 0, 0);
                a4 = __builtin_amdgcn_mfma_f32_16x16x32_bf16(ah, bl, a4, 0, 0, 0);
            }
            if (lm < 15) {
                float bb = ld(b4, lm) + ld(encb, lm);
                #pragma unroll
                for (int j = 0; j < 4; j++) {
                    int row = mt * 16 + quad * 4 + j;
                    int t = t0 + row;
                    if (t < T_DATA) {
                        float x = a4[j] + bb + Sc[row * 16 + lm + 1] + Sc[1024 + row * 16 + lm + 1];
                        x = fminf(fmaxf(x, -40.f), 40.f);
                        float sg = 1.f / (1.f + expf(-x));
                        ((float*)out)[(size_t)t * 15 + lm] = sg;
                    }
                }
            }
        }
    }
}

__global__ void __launch_bounds__(256, 2) k_convmlp(
    const void* Se, const void* V,
    const unsigned char* in_e, const unsigned char* in_i,
    const float* ker_e, const float* ker_i,
    const unsigned short* W1h, const unsigned short* W1l, const void* b1, const void* a1p,
    const unsigned short* W2h, const unsigned short* W2l, const void* b2, const void* a2p,
    const unsigned short* W3h, const unsigned short* W3l, const void* b3, const void* a3p,
    const unsigned short* W4h, const unsigned short* W4l, const void* b4,
    const void* encb, unsigned short* AloBase, void* out) {
    // union: kernel staging kef/kif (25728 B) then MLP Ahi (32768 B)
    __shared__ __align__(16) unsigned char smem[32768];
    __shared__ __align__(16) float Sc[2 * 64 * 16];   // [arr][row][s]
    __shared__ int sfl;

    float* kef = (float*)smem;             // [16][201]
    float* kif = kef + 16 * 201;           // end byte 25728

    int tid = threadIdx.x;
    int lane = tid & 63, wave = tid >> 6;
    int t0 = blockIdx.x * 64;
    unsigned short* AloG = AloBase + (size_t)blockIdx.x * 64 * 256;

    // hoisted layer-1 B preload (valid in BOTH dtype modes); 20 coalesced
    // 16B loads issued first; latency hides under kernel staging + conv.
    bf16x8 Bh1[5][4];
    #pragma unroll
    for (int ks = 0; ks < 5; ks++)
        #pragma unroll
        for (int nt = 0; nt < 4; nt++)
            Bh1[ks][nt] = *(const bf16x8*)(W1h + (size_t)((((wave * 4 + nt) * 5 + ks) * 64 + lane) << 3));

    // stage kernel coefficients (f32, 3200 each)
    for (int idx = tid; idx < 3200; idx += 256) {
        int s2 = idx / 200, j = idx - s2 * 200;
        kef[s2 * 201 + j] = ker_e[idx];
        kif[s2 * 201 + j] = ker_i[idx];
    }
    int f = detect_bf(Se, &sfl);   // its double-sync covers the staging above

    {   // conv: e/i split, 8 rows/thread, global windows, LDS kernel broadcast
        int arr = tid >> 7;                   // 0: e-array, 1: i-array
        int g8 = ((tid >> 4) & 7) * 8;        // base output row (0..56)
        int s  = tid & 15;                    // subunit
        const unsigned char* src = arr ? in_i : in_e;
        const float* kf = arr ? kif : kef;
        float w[8], acc8[8];
        #pragma unroll
        for (int i = 0; i < 8; i++) {
            int t = t0 + g8 + i;
            w[i] = (t < T_DATA) ? (float)src[(size_t)t * 16 + s] : 0.f;
            acc8[i] = 0.f;
        }
        #pragma unroll 8
        for (int j = 0; j < 200; j++) {
            float kj = kf[s * 201 + j];
            #pragma unroll
            for (int i = 0; i < 8; i++) acc8[i] += w[i] * kj;
            int t = t0 + g8 - j - 1;
            float nv = (t >= 0) ? (float)src[(size_t)t * 16 + s] : 0.f;
            #pragma unroll
            for (int i = 7; i > 0; i--) w[i] = w[i - 1];
            w[0] = nv;
        }
        #pragma unroll
        for (int i = 0; i < 8; i++)
            Sc[arr * 1024 + (g8 + i) * 16 + s] = acc8[i];
    }
    __syncthreads();   // Sc ready; kernel staging dead -> union free for Ahi

    unsigned short* Ahi = (unsigned short*)smem;
    if (f)
        mlp_body<true>(V, W1h, W1l, b1, a1p, W2h, W2l, b2, a2p, W3h, W3l, b3, a3p,
                       W4h, W4l, b4, encb, Sc, out, Ahi, AloG, Bh1);
    else
        mlp_body<false>(V, W1h, W1l, b1, a1p, W2h, W2l, b2, a2p, W3h, W3l, b3, a3p,
                        W4h, W4l, b4, encb, Sc, out, Ahi, AloG, Bh1);
}

extern "C" void kernel_launch(void* const* d_in, const int* in_sizes, int n_in,
                              void* d_out, int out_size, void* d_ws, size_t ws_size,
                              hipStream_t stream) {
    const void* V    = d_in[0];
    const void* Se   = d_in[1];
    const void* Si   = d_in[2];
    const void* Ce   = d_in[3];
    const void* Ci   = d_in[4];
    const void* Ksyn = d_in[5];
    const void* tau  = d_in[6];
    const void* dly  = d_in[7];
    const void* encb = d_in[8];
    const void* W1   = d_in[9];
    const void* b1   = d_in[10];
    const void* a1   = d_in[11];
    const void* W2   = d_in[12];
    const void* b2   = d_in[13];
    const void* a2   = d_in[14];
    const void* W3   = d_in[15];
    const void* b3   = d_in[16];
    const void* a3   = d_in[17];
    const void* W4   = d_in[18];
    const void* b4   = d_in[19];

    char* w = (char*)d_ws;
    float* ker_e = (float*)(w + OFF_KERE);
    float* ker_i = (float*)(w + OFF_KERI);
    unsigned char* sh_e = (unsigned char*)(w + OFF_SHE);
    unsigned char* sh_i = (unsigned char*)(w + OFF_SHI);
    unsigned short* W1h = (unsigned short*)(w + OFF_W1H);
    unsigned short* W1l = (unsigned short*)(w + OFF_W1L);
    unsigned short* W2h = (unsigned short*)(w + OFF_W2H);
    unsigned short* W2l = (unsigned short*)(w + OFF_W2L);
    unsigned short* W3h = (unsigned short*)(w + OFF_W3H);
    unsigned short* W3l = (unsigned short*)(w + OFF_W3L);
    unsigned short* W4h = (unsigned short*)(w + OFF_W4H);
    unsigned short* W4l = (unsigned short*)(w + OFF_W4L);
    unsigned char* in_e = (unsigned char*)(w + OFF_INE);
    unsigned char* in_i = (unsigned char*)(w + OFF_INI);
    unsigned short* AloB = (unsigned short*)(w + OFF_ALO);

    k_tables<<<35, 256, 0, stream>>>(Se, Ksyn, tau, dly, Ce, Ci,
                                     ker_e, ker_i, sh_e, sh_i);
    k_spikes<<<5000, 256, 0, stream>>>(Se, Si, sh_e, sh_i, W1, W2, W3, W4,
                                       in_e, in_i,
                                       W1h, W1l, W2h, W2l, W3h, W3l, W4h, W4l);
    k_convmlp<<<313, 256, 0, stream>>>(Se, V, in_e, in_i, ker_e, ker_i,
                                       W1h, W1l, b1, a1, W2h, W2l, b2, a2,
                                       W3h, W3l, b3, a3, W4h, W4l, b4,
                                       encb, AloB, d_out);
}

// Round 10
// 357.022 us; speedup vs baseline: 1.3411x; 1.3411x over previous
//
#include <hip/hip_runtime.h>
#include <cstdint>
#include <cstddef>

#define T_DATA 20000
#define E_NO 2000
#define I_NO 500
#define SUB_NO 16
#define HID 256
#define T_SYN 200
#define T_ENC 80
#define W_IN 159   // 2*T_ENC-1

typedef __attribute__((ext_vector_type(8))) __bf16 bf16x8;
typedef __attribute__((ext_vector_type(8))) short short8;
typedef __attribute__((ext_vector_type(4))) float floatx4;
typedef __attribute__((ext_vector_type(4))) unsigned int uint4v;
typedef __attribute__((ext_vector_type(2))) unsigned int uint2v;

__device__ __forceinline__ float bf2f(unsigned short u) {
    union { unsigned int i; float f; } v; v.i = ((unsigned int)u) << 16; return v.f;
}
__device__ __forceinline__ unsigned short f2bf(float f) {
    union { float f; unsigned int i; } v; v.f = f;
    unsigned int r = v.i + 0x7FFFu + ((v.i >> 16) & 1u);
    return (unsigned short)(r >> 16);
}
__device__ __forceinline__ float inload(const void* p, int i, int isbf) {
    return isbf ? bf2f(((const unsigned short*)p)[i]) : ((const float*)p)[i];
}

// per-block dtype detection: scan first 1024 u32 words of S_e (4 KB, L2-hot).
__device__ __forceinline__ int detect_bf(const void* Se, int* sfl) {
    if (threadIdx.x == 0) *sfl = 0;
    __syncthreads();
    const unsigned int* w = (const unsigned int*)Se;
    int la = 0;
    #pragma unroll
    for (int i = 0; i < 4; i++)
        la |= (w[i * 256 + threadIdx.x] & 0xFFFFu) ? 1 : 0;
    if (la) atomicOr(sfl, 1);
    __syncthreads();
    return *sfl;
}

// ---------------- ws layout (bytes, all 16B aligned) ----------------
// W1..W4 stored in MFMA-FRAGMENT-PACKED order (see k_spikes): the
// B-fragment load for (tile,ks) is base + lane*16B -> fully coalesced.
#define OFF_KERE   16u        // 16*200 f32
#define OFF_KERI   12816u
#define OFF_SHE    25616u     // 2000 u8 (subunit*8 per e-synapse)
#define OFF_SHI    33616u     // 500 u8
#define OFF_W1H    35616u     // 40960 bf16 packed (16 tiles x 5 ks x 64 lanes x 8)
#define OFF_W1L    117536u
#define OFF_W2H    199456u    // 65536 bf16 packed (16 x 8 x 64 x 8)
#define OFF_W2L    330528u
#define OFF_W3H    461600u
#define OFF_W3L    592672u
#define OFF_W4H    723744u    // 4096 bf16 packed (8 ks x 64 lanes x 8), n zero-padded
#define OFF_W4L    731936u
#define OFF_INE    740128u    // 20000*16 u8
#define OFF_INI    1060128u   // total 1380128 bytes

// ================= kernel 1: tiny tables (ker + subunit maps) =================
__global__ void k_tables(const void* Se, const void* Ksyn, const void* tau_syn, const void* dly,
                         const void* Ce, const void* Ci,
                         float* ker_e, float* ker_i, unsigned char* sh_e, unsigned char* sh_i) {
    __shared__ int sfl;
    int f = detect_bf(Se, &sfl);
    int id = blockIdx.x * 256 + threadIdx.x;
    if (id < 6400) {
        int c = id < 3200 ? 0 : 1;
        int q = id - c * 3200;
        int s = q / 200, j = q - s * 200;
        float d = expf(inload(dly, s * 2 + c, f));
        float tt = fmaxf((float)j - d, 0.0f);
        float acc = 0.f;
        #pragma unroll
        for (int b = 0; b < 3; b++) {
            float tau = expf(inload(tau_syn, b * 3 + c, f));
            float x = tt / tau;
            acc += x * expf(-x) * inload(Ksyn, (s * 3 + b) * 3 + c, f);
        }
        (c == 0 ? ker_e : ker_i)[s * 200 + j] = acc;
    } else if (id < 8400) {
        int e = id - 6400;
        int a = 0;
        for (int s = 0; s < 16; s++) if (inload(Ce, s * E_NO + e, f) > 0.5f) a = s;
        sh_e[e] = (unsigned char)(a * 8);
    } else if (id < 8900) {
        int e = id - 8400;
        int a = 0;
        for (int s = 0; s < 16; s++) if (inload(Ci, s * I_NO + e, f) > 0.5f) a = s;
        sh_i[e] = (unsigned char)(a * 8);
    }
}

// ============ kernel 2: spike -> subunit counts (u8), BRANCHLESS ============
// Also absorbs W1-W4 hi/lo conversion into FRAGMENT-PACKED layout.
__device__ __forceinline__ void acc_slot(unsigned int b, unsigned int sh,
                                         unsigned long long& lo, unsigned long long& hi) {
    unsigned int up = sh >> 6;            // 1 if subunit >= 8
    unsigned int s6 = sh & 63;
    lo += (unsigned long long)(b & (up ^ 1u)) << s6;
    hi += (unsigned long long)(b & up) << s6;
}

__global__ void __launch_bounds__(256) k_spikes(const void* Se, const void* Si,
                         const unsigned char* sh_e, const unsigned char* sh_i,
                         const void* W1, const void* W2, const void* W3, const void* W4,
                         unsigned char* in_e, unsigned char* in_i,
                         unsigned short* W1h, unsigned short* W1l,
                         unsigned short* W2h, unsigned short* W2l,
                         unsigned short* W3h, unsigned short* W3l,
                         unsigned short* W4h, unsigned short* W4l) {
    __shared__ int sfl;
    __shared__ __align__(8) unsigned char she[E_NO];
    __shared__ __align__(8) unsigned char shi[I_NO];
    for (int i = threadIdx.x; i < E_NO / 4; i += 256)
        ((unsigned int*)she)[i] = ((const unsigned int*)sh_e)[i];
    for (int i = threadIdx.x; i < I_NO / 4; i += 256)
        ((unsigned int*)shi)[i] = ((const unsigned int*)sh_i)[i];
    int f = detect_bf(Se, &sfl);   // its syncthreads also covers table staging
    int lane = threadIdx.x & 63;
    int wave = threadIdx.x >> 6;
    int t = blockIdx.x * 4 + wave;
    unsigned long long e0 = 0, e1 = 0, i0 = 0, i1 = 0;
    if (f) {
        const uint4v* re = (const uint4v*)((const unsigned short*)Se + (size_t)t * E_NO);
        #pragma unroll
        for (int it = 0; it < 4; it++) {
            int c = it * 64 + lane;
            if (c < 250) {
                uint4v v = re[c];
                unsigned long long q = *(const unsigned long long*)&she[c * 8];
                #pragma unroll
                for (int w = 0; w < 4; w++) {
                    unsigned int x = v[w];
                    acc_slot((x >> 7) & 1u,  (unsigned int)(q >> (16 * w)) & 0xFFu, e0, e1);
                    acc_slot((x >> 23) & 1u, (unsigned int)(q >> (16 * w + 8)) & 0xFFu, e0, e1);
                }
            }
        }
        const uint2v* ri = (const uint2v*)((const unsigned short*)Si + (size_t)t * I_NO);
        #pragma unroll
        for (int it = 0; it < 2; it++) {
            int c = it * 64 + lane;
            if (c < 125) {
                uint2v v = ri[c];
                unsigned int q = *(const unsigned int*)&shi[c * 4];
                #pragma unroll
                for (int w = 0; w < 2; w++) {
                    unsigned int x = v[w];
                    acc_slot((x >> 7) & 1u,  (q >> (16 * w)) & 0xFFu, i0, i1);
                    acc_slot((x >> 23) & 1u, (q >> (16 * w + 8)) & 0xFFu, i0, i1);
                }
            }
        }
    } else {
        const uint4v* re = (const uint4v*)((const float*)Se + (size_t)t * E_NO);
        #pragma unroll
        for (int it = 0; it < 8; it++) {
            int c = it * 64 + lane;
            if (c < 500) {
                uint4v v = re[c];
                unsigned int q = *(const unsigned int*)&she[c * 4];
                #pragma unroll
                for (int w = 0; w < 4; w++)
                    acc_slot((v[w] >> 23) & 1u, (q >> (8 * w)) & 0xFFu, e0, e1);
            }
        }
        const uint2v* ri = (const uint2v*)((const float*)Si + (size_t)t * I_NO);
        #pragma unroll
        for (int it = 0; it < 4; it++) {
            int c = it * 64 + lane;
            if (c < 250) {
                uint2v v = ri[c];
                unsigned int q = *(const unsigned short*)&shi[c * 2];
                #pragma unroll
                for (int w = 0; w < 2; w++)
                    acc_slot((v[w] >> 23) & 1u, (q >> (8 * w)) & 0xFFu, i0, i1);
            }
        }
    }
    for (int off = 32; off; off >>= 1) {
        e0 += __shfl_xor(e0, off);
        e1 += __shfl_xor(e1, off);
        i0 += __shfl_xor(i0, off);
        i1 += __shfl_xor(i1, off);
    }
    if (lane < 16) {
        unsigned long long a = (lane < 8) ? e0 : e1;
        in_e[(size_t)t * 16 + lane] = (unsigned char)((a >> ((lane & 7) * 8)) & 0xFF);
    } else if (lane < 32) {
        int s = lane - 16;
        unsigned long long a = (s < 8) ? i0 : i1;
        in_i[(size_t)t * 16 + s] = (unsigned char)((a >> ((s & 7) * 8)) & 0xFF);
    }
    // ---- folded weight conversion into packed layout (688*256 = 176128) ----
    if (blockIdx.x < 688) {
        int q = blockIdx.x * 256 + threadIdx.x;   // packed linear index
        if (q < 40960) {                          // W1: KS=5, pad k 159->160
            int j = q & 7, l = (q >> 3) & 63, r = q >> 9;   // r in [0,80)
            int ks = r % 5, tile = r / 5;
            int n = tile * 16 + (l & 15);
            int k = ks * 32 + (l >> 4) * 8 + j;
            float v = (k < W_IN) ? inload(W1, n * W_IN + k, f) : 0.f;
            unsigned short hi = f2bf(v);
            W1h[q] = hi;
            W1l[q] = f2bf(v - bf2f(hi));
        } else if (q < 106496) {                  // W2: KS=8
            int p = q - 40960;
            int j = p & 7, l = (p >> 3) & 63, r = p >> 9;   // r in [0,128)
            int ks = r & 7, tile = r >> 3;
            int n = tile * 16 + (l & 15);
            int k = ks * 32 + (l >> 4) * 8 + j;
            float v = inload(W2, n * 256 + k, f);
            unsigned short hi = f2bf(v);
            W2h[p] = hi;
            W2l[p] = f2bf(v - bf2f(hi));
        } else if (q < 172032) {                  // W3: KS=8
            int p = q - 106496;
            int j = p & 7, l = (p >> 3) & 63, r = p >> 9;
            int ks = r & 7, tile = r >> 3;
            int n = tile * 16 + (l & 15);
            int k = ks * 32 + (l >> 4) * 8 + j;
            float v = inload(W3, n * 256 + k, f);
            unsigned short hi = f2bf(v);
            W3h[p] = hi;
            W3l[p] = f2bf(v - bf2f(hi));
        } else {                                  // W4: 8 ks, n zero-padded to 16
            int p = q - 172032;                   // [0,4096)
            int j = p & 7, l = (p >> 3) & 63, ks = p >> 9;
            int lm = l & 15, quad = l >> 4;
            float v = 0.f;
            if (lm < 15) v = inload(W4, lm * 256 + ks * 32 + quad * 8 + j, f);
            unsigned short hi = f2bf(v);
            W4h[p] = hi;
            W4l[p] = f2bf(v - bf2f(hi));
        }
    }
}

// ===== kernel 3: fused conv + MLP, M=64, packed B, RESTRUCTURED LDS conv ====
// r4 geometry + MLP (proven 355us / convmlp~89), with two deltas:
// (1) conv: e/i split (arr=tid>>7), 8 rows/thread, bf16-staged windows,
//     1 window-read + 1 kernel-broadcast per j (was 4 reads), unroll-8
//     register-renamed rotation. Conv live set ~24 regs — no spill path
//     (r9's spill came from 8 in-flight GLOBAL byte-loads + Bh1 under the
//     128-arch-reg split; windows stay in LDS here).
// (2) layers 2/3 B-preload chunked 4-ks (64 VGPR live, not 128) to keep
//     arch pressure safely under the 128 split.
// e/i conv sums kept separate, added at layer 4 — matches the reference
// (conv_e + conv_i computed separately) exactly.
template<bool BF>
__device__ __forceinline__ void mlp_body(
    const void* V,
    const unsigned short* W1h, const unsigned short* W1l, const void* b1, const void* a1p,
    const unsigned short* W2h, const unsigned short* W2l, const void* b2, const void* a2p,
    const unsigned short* W3h, const unsigned short* W3l, const void* b3, const void* a3p,
    const unsigned short* W4h, const unsigned short* W4l, const void* b4,
    const void* encb, const float* Sc, void* out,
    unsigned short* Ahi, unsigned short* Alo,
    const bf16x8 (&Bh1)[5][4])
{
    int tid = threadIdx.x;
    int lane = tid & 63, wave = tid >> 6;
    int lm = lane & 15, quad = lane >> 4;
    int t0 = blockIdx.x * 64;

    auto ld = [&](const void* p, int i) -> float {
        return BF ? bf2f(((const unsigned short*)p)[i]) : ((const float*)p)[i];
    };
    // packed fragment offsets (elements)
    auto boff1 = [&](int ks, int nt) { return (size_t)((((wave * 4 + nt) * 5 + ks) * 64 + lane) << 3); };
    auto boff  = [&](int ks, int nt) { return (size_t)((((wave * 4 + nt) * 8 + ks) * 64 + lane) << 3); };

    // stage layer-1 A: 64 rows x 160 cols, XOR kgroup swizzle (5-bit row mask)
    for (int idx = tid; idx < 64 * 160; idx += 256) {
        int m = idx / 160, k = idx - m * 160;
        int tg = t0 + m + k - (T_ENC - 1);
        float v = 0.f;
        if (k < W_IN && tg >= 0 && tg < T_DATA) v = ld(V, tg);
        unsigned short hi = f2bf(v);
        int col = (((k >> 3) ^ (m & 31)) << 3) | (k & 7);
        Ahi[m * 256 + col] = hi;
        if (!BF) Alo[m * 256 + col] = f2bf(v - bf2f(hi));
    }
    __syncthreads();

    floatx4 acc[4][4];   // [mt][nt] -> AGPRs
    auto aoff = [&](int mt, int ks) {
        int arow = mt * 16 + lm;
        return arow * 256 + ((((ks << 2) | quad) ^ (arow & 31)) << 3);
    };

    auto epi = [&](const void* bias, float alpha) {
        __syncthreads();
        #pragma unroll
        for (int mt = 0; mt < 4; mt++) {
            #pragma unroll
            for (int nt = 0; nt < 4; nt++) {
                int cn = wave * 64 + nt * 16 + lm;
                float bb = ld(bias, cn);
                #pragma unroll
                for (int j = 0; j < 4; j++) {
                    int row = mt * 16 + quad * 4 + j;
                    float h = acc[mt][nt][j] + bb;
                    h = (h >= 0.f) ? h : alpha * h;
                    unsigned short hi = f2bf(h);
                    int col = (((cn >> 3) ^ (row & 31)) << 3) | (cn & 7);
                    Ahi[row * 256 + col] = hi;
                    if (!BF) Alo[row * 256 + col] = f2bf(h - bf2f(hi));
                }
            }
        }
        __syncthreads();
    };

    floatx4 z = {0.f, 0.f, 0.f, 0.f};
    // ---- layer 1: K=160 (5 ks), B preloaded in Bh1 ----
    {
        #pragma unroll
        for (int mt = 0; mt < 4; mt++)
            #pragma unroll
            for (int nt = 0; nt < 4; nt++) acc[mt][nt] = z;
        if (BF) {
            #pragma unroll
            for (int ks = 0; ks < 5; ks++) {
                bf16x8 a[4];
                #pragma unroll
                for (int mt = 0; mt < 4; mt++) a[mt] = *(const bf16x8*)&Ahi[aoff(mt, ks)];
                #pragma unroll
                for (int nt = 0; nt < 4; nt++)
                    #pragma unroll
                    for (int mt = 0; mt < 4; mt++)
                        acc[mt][nt] = __builtin_amdgcn_mfma_f32_16x16x32_bf16(a[mt], Bh1[ks][nt], acc[mt][nt], 0, 0, 0);
            }
        } else {
            #pragma unroll
            for (int ks = 0; ks < 5; ks++) {
                bf16x8 ah[4], al[4];
                #pragma unroll
                for (int mt = 0; mt < 4; mt++) {
                    ah[mt] = *(const bf16x8*)&Ahi[aoff(mt, ks)];
                    al[mt] = *(const bf16x8*)&Alo[aoff(mt, ks)];
                }
                #pragma unroll
                for (int nt = 0; nt < 4; nt++) {
                    bf16x8 bh = Bh1[ks][nt];
                    bf16x8 bl = *(const bf16x8*)(W1l + boff1(ks, nt));
                    #pragma unroll
                    for (int mt = 0; mt < 4; mt++) {
                        acc[mt][nt] = __builtin_amdgcn_mfma_f32_16x16x32_bf16(ah[mt], bh, acc[mt][nt], 0, 0, 0);
                        acc[mt][nt] = __builtin_amdgcn_mfma_f32_16x16x32_bf16(al[mt], bh, acc[mt][nt], 0, 0, 0);
                        acc[mt][nt] = __builtin_amdgcn_mfma_f32_16x16x32_bf16(ah[mt], bl, acc[mt][nt], 0, 0, 0);
                    }
                }
            }
        }
        epi(b1, ld(a1p, 0));
    }
    // ---- layers 2,3: K=256 (8 ks, two 4-ks chunks to cap arch VGPR) ----
    const unsigned short* Whs[2] = {W2h, W3h};
    const unsigned short* Wls[2] = {W2l, W3l};
    const void* bs[2] = {b2, b3};
    const void* as_[2] = {a2p, a3p};
    for (int l = 0; l < 2; l++) {
        #pragma unroll
        for (int mt = 0; mt < 4; mt++)
            #pragma unroll
            for (int nt = 0; nt < 4; nt++) acc[mt][nt] = z;
        const unsigned short* Wh = Whs[l];
        const unsigned short* Wl = Wls[l];
        if (BF) {
            #pragma unroll
            for (int half = 0; half < 2; half++) {
                bf16x8 Bh[4][4];   // 64 VGPRs per chunk, 16 coalesced loads
                #pragma unroll
                for (int c = 0; c < 4; c++)
                    #pragma unroll
                    for (int nt = 0; nt < 4; nt++)
                        Bh[c][nt] = *(const bf16x8*)(Wh + boff(half * 4 + c, nt));
                #pragma unroll
                for (int c = 0; c < 4; c++) {
                    int ks = half * 4 + c;
                    bf16x8 a[4];
                    #pragma unroll
                    for (int mt = 0; mt < 4; mt++) a[mt] = *(const bf16x8*)&Ahi[aoff(mt, ks)];
                    #pragma unroll
                    for (int nt = 0; nt < 4; nt++)
                        #pragma unroll
                        for (int mt = 0; mt < 4; mt++)
                            acc[mt][nt] = __builtin_amdgcn_mfma_f32_16x16x32_bf16(a[mt], Bh[c][nt], acc[mt][nt], 0, 0, 0);
                }
            }
        } else {
            #pragma unroll
            for (int ks = 0; ks < 8; ks++) {
                bf16x8 ah[4], al[4];
                #pragma unroll
                for (int mt = 0; mt < 4; mt++) {
                    ah[mt] = *(const bf16x8*)&Ahi[aoff(mt, ks)];
                    al[mt] = *(const bf16x8*)&Alo[aoff(mt, ks)];
                }
                #pragma unroll
                for (int nt = 0; nt < 4; nt++) {
                    bf16x8 bh = *(const bf16x8*)(Wh + boff(ks, nt));
                    bf16x8 bl = *(const bf16x8*)(Wl + boff(ks, nt));
                    #pragma unroll
                    for (int mt = 0; mt < 4; mt++) {
                        acc[mt][nt] = __builtin_amdgcn_mfma_f32_16x16x32_bf16(ah[mt], bh, acc[mt][nt], 0, 0, 0);
                        acc[mt][nt] = __builtin_amdgcn_mfma_f32_16x16x32_bf16(al[mt], bh, acc[mt][nt], 0, 0, 0);
                        acc[mt][nt] = __builtin_amdgcn_mfma_f32_16x16x32_bf16(ah[mt], bl, acc[mt][nt], 0, 0, 0);
                    }
                }
            }
        }
        epi(bs[l], ld(as_[l], 0));
    }
    // ---- layer 4: N=16-padded packed, wave takes M-tile mt=wave ----
    {
        int mt = wave;
        floatx4 a4 = z;
        #pragma unroll
        for (int ks = 0; ks < 8; ks++) {
            bf16x8 ah = *(const bf16x8*)&Ahi[aoff(mt, ks)];
            bf16x8 bh = *(const bf16x8*)(W4h + (size_t)((ks * 64 + lane) << 3));
            a4 = __builtin_amdgcn_mfma_f32_16x16x32_bf16(ah, bh, a4, 0, 0, 0);
            if (!BF) {
                bf16x8 al = *(const bf16x8*)&Alo[aoff(mt, ks)];
                bf16x8 bl = *(const bf16x8*)(W4l + (size_t)((ks * 64 + lane) << 3));
                a4 = __builtin_amdgcn_mfma_f32_16x16x32_bf16(al, bh, a4, 0, 0, 0);
                a4 = __builtin_amdgcn_mfma_f32_16x16x32_bf16(ah, bl, a4, 0, 0, 0);
            }
        }
        if (lm < 15) {
            float bb = ld(b4, lm) + ld(encb, lm);
            #pragma unroll
            for (int j = 0; j < 4; j++) {
                int row = mt * 16 + quad * 4 + j;
                int t = t0 + row;
                if (t < T_DATA) {
                    float x = a4[j] + bb + Sc[row * 16 + lm + 1] + Sc[1024 + row * 16 + lm + 1];
                    x = fminf(fmaxf(x, -40.f), 40.f);
                    float sg = 1.f / (1.f + expf(-x));
                    if (BF) ((unsigned short*)out)[(size_t)t * 15 + lm] = f2bf(sg);
                    else    ((float*)out)[(size_t)t * 15 + lm] = sg;
                }
            }
        }
    }
}

__global__ void __launch_bounds__(256, 2) k_convmlp(
    const void* Se, const void* V,
    const unsigned char* in_e, const unsigned char* in_i,
    const float* ker_e, const float* ker_i,
    const unsigned short* W1h, const unsigned short* W1l, const void* b1, const void* a1p,
    const unsigned short* W2h, const unsigned short* W2l, const void* b2, const void* a2p,
    const unsigned short* W3h, const unsigned short* W3l, const void* b3, const void* a3p,
    const unsigned short* W4h, const unsigned short* W4l, const void* b4,
    const void* encb, void* out) {
    // union: conv staging {se16/si16 bf16 + kef/kif f32, 43.6 KB} then MLP
    // {Ahi+Alo, 64 KB} — sequential phases. + Sc[2][64][16] (8 KB).
    __shared__ __align__(16) unsigned char smem[65536];
    __shared__ __align__(16) float Sc[2 * 64 * 16];   // [arr][row][s]
    __shared__ int sfl;

    unsigned short* se16 = (unsigned short*)smem;        // [263*17] bf16
    unsigned short* si16 = se16 + 4472;                  // 16B-aligned
    float* kef = (float*)(smem + 17888);                 // [16][201] f32
    float* kif = kef + 16 * 201;                         // end byte 43616

    int tid = threadIdx.x;
    int lane = tid & 63, wave = tid >> 6;
    int t0 = blockIdx.x * 64;

    // hoisted layer-1 B preload (valid in BOTH dtype modes); 20 coalesced
    // 16B loads; latency hides under conv staging + conv compute.
    bf16x8 Bh1[5][4];
    #pragma unroll
    for (int ks = 0; ks < 5; ks++)
        #pragma unroll
        for (int nt = 0; nt < 4; nt++)
            Bh1[ks][nt] = *(const bf16x8*)(W1h + (size_t)((((wave * 4 + nt) * 5 + ks) * 64 + lane) << 3));

    // stage conv windows as bf16 (counts <=255 exact) + kernel coeffs
    for (int idx = tid; idx < 263 * 4; idx += 256) {
        int r = idx >> 2, wi = idx & 3;
        int t = t0 - 199 + r;
        unsigned int ve = 0, vi = 0;
        if (t >= 0 && t < T_DATA) {
            ve = ((const unsigned int*)in_e)[t * 4 + wi];
            vi = ((const unsigned int*)in_i)[t * 4 + wi];
        }
        #pragma unroll
        for (int b = 0; b < 4; b++) {
            se16[r * 17 + wi * 4 + b] = f2bf((float)((ve >> (8 * b)) & 0xFF));
            si16[r * 17 + wi * 4 + b] = f2bf((float)((vi >> (8 * b)) & 0xFF));
        }
    }
    for (int idx = tid; idx < 3200; idx += 256) {
        int s2 = idx / 200, j = idx - s2 * 200;
        kef[s2 * 201 + j] = ker_e[idx];
        kif[s2 * 201 + j] = ker_i[idx];
    }
    int f = detect_bf(Se, &sfl);   // its double-sync covers the staging above

    {   // conv: e/i split, 8 rows/thread, 2 LDS reads/j, unroll-8 rotation
        int arr = tid >> 7;                   // 0: e-array, 1: i-array
        int g8 = ((tid >> 4) & 7) * 8;        // base output row (0..56)
        int s  = tid & 15;                    // subunit
        const unsigned short* src = arr ? si16 : se16;
        const float* kf = arr ? kif : kef;
        float w[8], acc8[8];
        #pragma unroll
        for (int i = 0; i < 8; i++) {
            w[i] = bf2f(src[(g8 + i + 199) * 17 + s]);
            acc8[i] = 0.f;
        }
        #pragma unroll 8
        for (int j = 0; j < 200; j++) {
            float kj = kf[s * 201 + j];
            #pragma unroll
            for (int i = 0; i < 8; i++) acc8[i] += w[i] * kj;
            int lr = g8 + 198 - j; lr = lr < 0 ? 0 : lr;   // j=199 value unused
            float nv = bf2f(src[lr * 17 + s]);
            #pragma unroll
            for (int i = 7; i > 0; i--) w[i] = w[i - 1];
            w[0] = nv;
        }
        #pragma unroll
        for (int i = 0; i < 8; i++)
            Sc[arr * 1024 + (g8 + i) * 16 + s] = acc8[i];
    }
    __syncthreads();   // Sc ready; conv staging dead -> union free for Ahi/Alo

    unsigned short* Ahi = (unsigned short*)smem;
    unsigned short* Alo = Ahi + 64 * 256;
    if (f)
        mlp_body<true>(V, W1h, W1l, b1, a1p, W2h, W2l, b2, a2p, W3h, W3l, b3, a3p,
                       W4h, W4l, b4, encb, Sc, out, Ahi, Alo, Bh1);
    else
        mlp_body<false>(V, W1h, W1l, b1, a1p, W2h, W2l, b2, a2p, W3h, W3l, b3, a3p,
                        W4h, W4l, b4, encb, Sc, out, Ahi, Alo, Bh1);
}

extern "C" void kernel_launch(void* const* d_in, const int* in_sizes, int n_in,
                              void* d_out, int out_size, void* d_ws, size_t ws_size,
                              hipStream_t stream) {
    const void* V    = d_in[0];
    const void* Se   = d_in[1];
    const void* Si   = d_in[2];
    const void* Ce   = d_in[3];
    const void* Ci   = d_in[4];
    const void* Ksyn = d_in[5];
    const void* tau  = d_in[6];
    const void* dly  = d_in[7];
    const void* encb = d_in[8];
    const void* W1   = d_in[9];
    const void* b1   = d_in[10];
    const void* a1   = d_in[11];
    const void* W2   = d_in[12];
    const void* b2   = d_in[13];
    const void* a2   = d_in[14];
    const void* W3   = d_in[15];
    const void* b3   = d_in[16];
    const void* a3   = d_in[17];
    const void* W4   = d_in[18];
    const void* b4   = d_in[19];

    char* w = (char*)d_ws;
    float* ker_e = (float*)(w + OFF_KERE);
    float* ker_i = (float*)(w + OFF_KERI);
    unsigned char* sh_e = (unsigned char*)(w + OFF_SHE);
    unsigned char* sh_i = (unsigned char*)(w + OFF_SHI);
    unsigned short* W1h = (unsigned short*)(w + OFF_W1H);
    unsigned short* W1l = (unsigned short*)(w + OFF_W1L);
    unsigned short* W2h = (unsigned short*)(w + OFF_W2H);
    unsigned short* W2l = (unsigned short*)(w + OFF_W2L);
    unsigned short* W3h = (unsigned short*)(w + OFF_W3H);
    unsigned short* W3l = (unsigned short*)(w + OFF_W3L);
    unsigned short* W4h = (unsigned short*)(w + OFF_W4H);
    unsigned short* W4l = (unsigned short*)(w + OFF_W4L);
    unsigned char* in_e = (unsigned char*)(w + OFF_INE);
    unsigned char* in_i = (unsigned char*)(w + OFF_INI);

    k_tables<<<35, 256, 0, stream>>>(Se, Ksyn, tau, dly, Ce, Ci,
                                     ker_e, ker_i, sh_e, sh_i);
    k_spikes<<<5000, 256, 0, stream>>>(Se, Si, sh_e, sh_i, W1, W2, W3, W4,
                                       in_e, in_i,
                                       W1h, W1l, W2h, W2l, W3h, W3l, W4h, W4l);
    k_convmlp<<<313, 256, 0, stream>>>(Se, V, in_e, in_i, ker_e, ker_i,
                                       W1h, W1l, b1, a1, W2h, W2l, b2, a2,
                                       W3h, W3l, b3, a3, W4h, W4l, b4,
                                       encb, d_out);
}

// Round 11
// 355.615 us; speedup vs baseline: 1.3464x; 1.0040x over previous
//
#include <hip/hip_runtime.h>
#include <cstdint>
#include <cstddef>

#define T_DATA 20000
#define E_NO 2000
#define I_NO 500
#define SUB_NO 16
#define HID 256
#define T_SYN 200
#define T_ENC 80
#define W_IN 159   // 2*T_ENC-1

typedef __attribute__((ext_vector_type(8))) __bf16 bf16x8;
typedef __attribute__((ext_vector_type(8))) short short8;
typedef __attribute__((ext_vector_type(4))) float floatx4;
typedef __attribute__((ext_vector_type(4))) unsigned int uint4v;
typedef __attribute__((ext_vector_type(2))) unsigned int uint2v;

__device__ __forceinline__ float bf2f(unsigned short u) {
    union { unsigned int i; float f; } v; v.i = ((unsigned int)u) << 16; return v.f;
}
__device__ __forceinline__ unsigned short f2bf(float f) {
    union { float f; unsigned int i; } v; v.f = f;
    unsigned int r = v.i + 0x7FFFu + ((v.i >> 16) & 1u);
    return (unsigned short)(r >> 16);
}
__device__ __forceinline__ float inload(const void* p, int i, int isbf) {
    return isbf ? bf2f(((const unsigned short*)p)[i]) : ((const float*)p)[i];
}

// per-block dtype detection: scan first 1024 u32 words of S_e (4 KB, L2-hot).
__device__ __forceinline__ int detect_bf(const void* Se, int* sfl) {
    if (threadIdx.x == 0) *sfl = 0;
    __syncthreads();
    const unsigned int* w = (const unsigned int*)Se;
    int la = 0;
    #pragma unroll
    for (int i = 0; i < 4; i++)
        la |= (w[i * 256 + threadIdx.x] & 0xFFFFu) ? 1 : 0;
    if (la) atomicOr(sfl, 1);
    __syncthreads();
    return *sfl;
}

// ---------------- ws layout (bytes, all 16B aligned) ----------------
// W1..W4 stored in MFMA-FRAGMENT-PACKED order (see k_spikes): the
// B-fragment load for (tile,ks) is base + lane*16B -> fully coalesced.
#define OFF_KERE   16u        // 16*200 f32
#define OFF_KERI   12816u
#define OFF_SHE    25616u     // 2000 u8 (subunit*8 per e-synapse)
#define OFF_SHI    33616u     // 500 u8
#define OFF_W1H    35616u     // 40960 bf16 packed (16 tiles x 5 ks x 64 lanes x 8)
#define OFF_W1L    117536u
#define OFF_W2H    199456u    // 65536 bf16 packed (16 x 8 x 64 x 8)
#define OFF_W2L    330528u
#define OFF_W3H    461600u
#define OFF_W3L    592672u
#define OFF_W4H    723744u    // 4096 bf16 packed (8 ks x 64 lanes x 8), n zero-padded
#define OFF_W4L    731936u
#define OFF_INE    740128u    // 20000*16 u8
#define OFF_INI    1060128u   // total 1380128 bytes

// ================= kernel 1: tiny tables (ker + subunit maps) =================
__global__ void k_tables(const void* Se, const void* Ksyn, const void* tau_syn, const void* dly,
                         const void* Ce, const void* Ci,
                         float* ker_e, float* ker_i, unsigned char* sh_e, unsigned char* sh_i) {
    __shared__ int sfl;
    int f = detect_bf(Se, &sfl);
    int id = blockIdx.x * 256 + threadIdx.x;
    if (id < 6400) {
        int c = id < 3200 ? 0 : 1;
        int q = id - c * 3200;
        int s = q / 200, j = q - s * 200;
        float d = expf(inload(dly, s * 2 + c, f));
        float tt = fmaxf((float)j - d, 0.0f);
        float acc = 0.f;
        #pragma unroll
        for (int b = 0; b < 3; b++) {
            float tau = expf(inload(tau_syn, b * 3 + c, f));
            float x = tt / tau;
            acc += x * expf(-x) * inload(Ksyn, (s * 3 + b) * 3 + c, f);
        }
        (c == 0 ? ker_e : ker_i)[s * 200 + j] = acc;
    } else if (id < 8400) {
        int e = id - 6400;
        int a = 0;
        for (int s = 0; s < 16; s++) if (inload(Ce, s * E_NO + e, f) > 0.5f) a = s;
        sh_e[e] = (unsigned char)(a * 8);
    } else if (id < 8900) {
        int e = id - 8400;
        int a = 0;
        for (int s = 0; s < 16; s++) if (inload(Ci, s * I_NO + e, f) > 0.5f) a = s;
        sh_i[e] = (unsigned char)(a * 8);
    }
}

// ============ kernel 2: spike -> subunit counts (u8), BRANCHLESS ============
// Also absorbs W1-W4 hi/lo conversion into FRAGMENT-PACKED layout.
__device__ __forceinline__ void acc_slot(unsigned int b, unsigned int sh,
                                         unsigned long long& lo, unsigned long long& hi) {
    unsigned int up = sh >> 6;            // 1 if subunit >= 8
    unsigned int s6 = sh & 63;
    lo += (unsigned long long)(b & (up ^ 1u)) << s6;
    hi += (unsigned long long)(b & up) << s6;
}

__global__ void __launch_bounds__(256) k_spikes(const void* Se, const void* Si,
                         const unsigned char* sh_e, const unsigned char* sh_i,
                         const void* W1, const void* W2, const void* W3, const void* W4,
                         unsigned char* in_e, unsigned char* in_i,
                         unsigned short* W1h, unsigned short* W1l,
                         unsigned short* W2h, unsigned short* W2l,
                         unsigned short* W3h, unsigned short* W3l,
                         unsigned short* W4h, unsigned short* W4l) {
    __shared__ int sfl;
    __shared__ __align__(8) unsigned char she[E_NO];
    __shared__ __align__(8) unsigned char shi[I_NO];
    for (int i = threadIdx.x; i < E_NO / 4; i += 256)
        ((unsigned int*)she)[i] = ((const unsigned int*)sh_e)[i];
    for (int i = threadIdx.x; i < I_NO / 4; i += 256)
        ((unsigned int*)shi)[i] = ((const unsigned int*)sh_i)[i];
    int f = detect_bf(Se, &sfl);   // its syncthreads also covers table staging
    int lane = threadIdx.x & 63;
    int wave = threadIdx.x >> 6;
    int t = blockIdx.x * 4 + wave;
    unsigned long long e0 = 0, e1 = 0, i0 = 0, i1 = 0;
    if (f) {
        const uint4v* re = (const uint4v*)((const unsigned short*)Se + (size_t)t * E_NO);
        #pragma unroll
        for (int it = 0; it < 4; it++) {
            int c = it * 64 + lane;
            if (c < 250) {
                uint4v v = re[c];
                unsigned long long q = *(const unsigned long long*)&she[c * 8];
                #pragma unroll
                for (int w = 0; w < 4; w++) {
                    unsigned int x = v[w];
                    acc_slot((x >> 7) & 1u,  (unsigned int)(q >> (16 * w)) & 0xFFu, e0, e1);
                    acc_slot((x >> 23) & 1u, (unsigned int)(q >> (16 * w + 8)) & 0xFFu, e0, e1);
                }
            }
        }
        const uint2v* ri = (const uint2v*)((const unsigned short*)Si + (size_t)t * I_NO);
        #pragma unroll
        for (int it = 0; it < 2; it++) {
            int c = it * 64 + lane;
            if (c < 125) {
                uint2v v = ri[c];
                unsigned int q = *(const unsigned int*)&shi[c * 4];
                #pragma unroll
                for (int w = 0; w < 2; w++) {
                    unsigned int x = v[w];
                    acc_slot((x >> 7) & 1u,  (q >> (16 * w)) & 0xFFu, i0, i1);
                    acc_slot((x >> 23) & 1u, (q >> (16 * w + 8)) & 0xFFu, i0, i1);
                }
            }
        }
    } else {
        const uint4v* re = (const uint4v*)((const float*)Se + (size_t)t * E_NO);
        #pragma unroll
        for (int it = 0; it < 8; it++) {
            int c = it * 64 + lane;
            if (c < 500) {
                uint4v v = re[c];
                unsigned int q = *(const unsigned int*)&she[c * 4];
                #pragma unroll
                for (int w = 0; w < 4; w++)
                    acc_slot((v[w] >> 23) & 1u, (q >> (8 * w)) & 0xFFu, e0, e1);
            }
        }
        const uint2v* ri = (const uint2v*)((const float*)Si + (size_t)t * I_NO);
        #pragma unroll
        for (int it = 0; it < 4; it++) {
            int c = it * 64 + lane;
            if (c < 250) {
                uint2v v = ri[c];
                unsigned int q = *(const unsigned short*)&shi[c * 2];
                #pragma unroll
                for (int w = 0; w < 2; w++)
                    acc_slot((v[w] >> 23) & 1u, (q >> (8 * w)) & 0xFFu, i0, i1);
            }
        }
    }
    for (int off = 32; off; off >>= 1) {
        e0 += __shfl_xor(e0, off);
        e1 += __shfl_xor(e1, off);
        i0 += __shfl_xor(i0, off);
        i1 += __shfl_xor(i1, off);
    }
    if (lane < 16) {
        unsigned long long a = (lane < 8) ? e0 : e1;
        in_e[(size_t)t * 16 + lane] = (unsigned char)((a >> ((lane & 7) * 8)) & 0xFF);
    } else if (lane < 32) {
        int s = lane - 16;
        unsigned long long a = (s < 8) ? i0 : i1;
        in_i[(size_t)t * 16 + s] = (unsigned char)((a >> ((s & 7) * 8)) & 0xFF);
    }
    // ---- folded weight conversion into packed layout (688*256 = 176128) ----
    if (blockIdx.x < 688) {
        int q = blockIdx.x * 256 + threadIdx.x;   // packed linear index
        if (q < 40960) {                          // W1: KS=5, pad k 159->160
            int j = q & 7, l = (q >> 3) & 63, r = q >> 9;   // r in [0,80)
            int ks = r % 5, tile = r / 5;
            int n = tile * 16 + (l & 15);
            int k = ks * 32 + (l >> 4) * 8 + j;
            float v = (k < W_IN) ? inload(W1, n * W_IN + k, f) : 0.f;
            unsigned short hi = f2bf(v);
            W1h[q] = hi;
            W1l[q] = f2bf(v - bf2f(hi));
        } else if (q < 106496) {                  // W2: KS=8
            int p = q - 40960;
            int j = p & 7, l = (p >> 3) & 63, r = p >> 9;   // r in [0,128)
            int ks = r & 7, tile = r >> 3;
            int n = tile * 16 + (l & 15);
            int k = ks * 32 + (l >> 4) * 8 + j;
            float v = inload(W2, n * 256 + k, f);
            unsigned short hi = f2bf(v);
            W2h[p] = hi;
            W2l[p] = f2bf(v - bf2f(hi));
        } else if (q < 172032) {                  // W3: KS=8
            int p = q - 106496;
            int j = p & 7, l = (p >> 3) & 63, r = p >> 9;
            int ks = r & 7, tile = r >> 3;
            int n = tile * 16 + (l & 15);
            int k = ks * 32 + (l >> 4) * 8 + j;
            float v = inload(W3, n * 256 + k, f);
            unsigned short hi = f2bf(v);
            W3h[p] = hi;
            W3l[p] = f2bf(v - bf2f(hi));
        } else {                                  // W4: 8 ks, n zero-padded to 16
            int p = q - 172032;                   // [0,4096)
            int j = p & 7, l = (p >> 3) & 63, ks = p >> 9;
            int lm = l & 15, quad = l >> 4;
            float v = 0.f;
            if (lm < 15) v = inload(W4, lm * 256 + ks * 32 + quad * 8 + j, f);
            unsigned short hi = f2bf(v);
            W4h[p] = hi;
            W4l[p] = f2bf(v - bf2f(hi));
        }
    }
}

// ===== kernel 3: fused conv + MLP — ROLLED LOOPS (I$ footprint test) =====
// Same arithmetic + order as r10 (bit-identical output). Single variable vs
// r10: the MLP is ONE generic rolled layer body (#pragma unroll 1 over l and
// ks; pointer select via ternaries, no scratch arrays) + one epilogue copy;
// layer-4 ks rolled; Bh1 hoist dropped; conv unroll 8 -> 2. Hot-path unique
// instructions drop ~10x (2.5-3K -> ~300). Theory: each block executes the
// hot path ONCE, so per-CU L1 I$ is cold for the whole kernel; ~350 code
// lines from L2 at ~200cyc is the tens-of-us stall no data-path counter
// shows — consistent with all six null rounds (r3/r5-r10).
template<bool BF>
__device__ void mlp_body(
    const void* V,
    const unsigned short* W1h, const unsigned short* W1l, const void* b1, const void* a1p,
    const unsigned short* W2h, const unsigned short* W2l, const void* b2, const void* a2p,
    const unsigned short* W3h, const unsigned short* W3l, const void* b3, const void* a3p,
    const unsigned short* W4h, const unsigned short* W4l, const void* b4,
    const void* encb, const float* Sc, void* out,
    unsigned short* Ahi, unsigned short* Alo)
{
    int tid = threadIdx.x;
    int lane = tid & 63, wave = tid >> 6;
    int lm = lane & 15, quad = lane >> 4;
    int t0 = blockIdx.x * 64;

    auto ld = [&](const void* p, int i) -> float {
        return BF ? bf2f(((const unsigned short*)p)[i]) : ((const float*)p)[i];
    };

    // stage layer-1 A: 64 rows x 160 cols, XOR kgroup swizzle (5-bit row mask)
    for (int idx = tid; idx < 64 * 160; idx += 256) {
        int m = idx / 160, k = idx - m * 160;
        int tg = t0 + m + k - (T_ENC - 1);
        float v = 0.f;
        if (k < W_IN && tg >= 0 && tg < T_DATA) v = ld(V, tg);
        unsigned short hi = f2bf(v);
        int col = (((k >> 3) ^ (m & 31)) << 3) | (k & 7);
        Ahi[m * 256 + col] = hi;
        if (!BF) Alo[m * 256 + col] = f2bf(v - bf2f(hi));
    }
    __syncthreads();

    floatx4 acc[4][4];   // [mt][nt] -> AGPRs (static-indexed only)
    auto aoff = [&](int mt, int ks) {
        int arow = mt * 16 + lm;
        return arow * 256 + ((((ks << 2) | quad) ^ (arow & 31)) << 3);
    };

    floatx4 z = {0.f, 0.f, 0.f, 0.f};

    // ---- layers 1-3: one rolled body ----
    #pragma unroll 1
    for (int l = 0; l < 3; l++) {
        const unsigned short* Wh = (l == 0) ? W1h : ((l == 1) ? W2h : W3h);
        const unsigned short* Wl = (l == 0) ? W1l : ((l == 1) ? W2l : W3l);
        const void* bb = (l == 0) ? b1 : ((l == 1) ? b2 : b3);
        const void* aa = (l == 0) ? a1p : ((l == 1) ? a2p : a3p);
        int KS = (l == 0) ? 5 : 8;

        #pragma unroll
        for (int mt = 0; mt < 4; mt++)
            #pragma unroll
            for (int nt = 0; nt < 4; nt++) acc[mt][nt] = z;

        #pragma unroll 1
        for (int ks = 0; ks < KS; ks++) {
            bf16x8 a[4];
            #pragma unroll
            for (int mt = 0; mt < 4; mt++) a[mt] = *(const bf16x8*)&Ahi[aoff(mt, ks)];
            if (BF) {
                #pragma unroll
                for (int nt = 0; nt < 4; nt++) {
                    bf16x8 b = *(const bf16x8*)(Wh + (size_t)((((wave * 4 + nt) * KS + ks) * 64 + lane) << 3));
                    #pragma unroll
                    for (int mt = 0; mt < 4; mt++)
                        acc[mt][nt] = __builtin_amdgcn_mfma_f32_16x16x32_bf16(a[mt], b, acc[mt][nt], 0, 0, 0);
                }
            } else {
                bf16x8 al[4];
                #pragma unroll
                for (int mt = 0; mt < 4; mt++) al[mt] = *(const bf16x8*)&Alo[aoff(mt, ks)];
                #pragma unroll
                for (int nt = 0; nt < 4; nt++) {
                    size_t bo = (size_t)((((wave * 4 + nt) * KS + ks) * 64 + lane) << 3);
                    bf16x8 bh = *(const bf16x8*)(Wh + bo);
                    bf16x8 bl = *(const bf16x8*)(Wl + bo);
                    #pragma unroll
                    for (int mt = 0; mt < 4; mt++) {
                        acc[mt][nt] = __builtin_amdgcn_mfma_f32_16x16x32_bf16(a[mt], bh, acc[mt][nt], 0, 0, 0);
                        acc[mt][nt] = __builtin_amdgcn_mfma_f32_16x16x32_bf16(al[mt], bh, acc[mt][nt], 0, 0, 0);
                        acc[mt][nt] = __builtin_amdgcn_mfma_f32_16x16x32_bf16(a[mt], bl, acc[mt][nt], 0, 0, 0);
                    }
                }
            }
        }

        // epilogue (single code copy, inlined here once)
        float alpha = ld(aa, 0);
        __syncthreads();
        #pragma unroll
        for (int mt = 0; mt < 4; mt++) {
            #pragma unroll
            for (int nt = 0; nt < 4; nt++) {
                int cn = wave * 64 + nt * 16 + lm;
                float bv = ld(bb, cn);
                #pragma unroll
                for (int j = 0; j < 4; j++) {
                    int row = mt * 16 + quad * 4 + j;
                    float h = acc[mt][nt][j] + bv;
                    h = (h >= 0.f) ? h : alpha * h;
                    unsigned short hi = f2bf(h);
                    int col = (((cn >> 3) ^ (row & 31)) << 3) | (cn & 7);
                    Ahi[row * 256 + col] = hi;
                    if (!BF) Alo[row * 256 + col] = f2bf(h - bf2f(hi));
                }
            }
        }
        __syncthreads();
    }

    // ---- layer 4: N=16-padded packed, wave takes M-tile mt=wave ----
    {
        int mt = wave;
        floatx4 a4 = z;
        #pragma unroll 1
        for (int ks = 0; ks < 8; ks++) {
            bf16x8 ah = *(const bf16x8*)&Ahi[aoff(mt, ks)];
            bf16x8 bh = *(const bf16x8*)(W4h + (size_t)((ks * 64 + lane) << 3));
            a4 = __builtin_amdgcn_mfma_f32_16x16x32_bf16(ah, bh, a4, 0, 0, 0);
            if (!BF) {
                bf16x8 al = *(const bf16x8*)&Alo[aoff(mt, ks)];
                bf16x8 bl = *(const bf16x8*)(W4l + (size_t)((ks * 64 + lane) << 3));
                a4 = __builtin_amdgcn_mfma_f32_16x16x32_bf16(al, bh, a4, 0, 0, 0);
                a4 = __builtin_amdgcn_mfma_f32_16x16x32_bf16(ah, bl, a4, 0, 0, 0);
            }
        }
        if (lm < 15) {
            float bb = ld(b4, lm) + ld(encb, lm);
            #pragma unroll
            for (int j = 0; j < 4; j++) {
                int row = mt * 16 + quad * 4 + j;
                int t = t0 + row;
                if (t < T_DATA) {
                    float x = a4[j] + bb + Sc[row * 16 + lm + 1] + Sc[1024 + row * 16 + lm + 1];
                    x = fminf(fmaxf(x, -40.f), 40.f);
                    float sg = 1.f / (1.f + expf(-x));
                    if (BF) ((unsigned short*)out)[(size_t)t * 15 + lm] = f2bf(sg);
                    else    ((float*)out)[(size_t)t * 15 + lm] = sg;
                }
            }
        }
    }
}

__global__ void __launch_bounds__(256, 2) k_convmlp(
    const void* Se, const void* V,
    const unsigned char* in_e, const unsigned char* in_i,
    const float* ker_e, const float* ker_i,
    const unsigned short* W1h, const unsigned short* W1l, const void* b1, const void* a1p,
    const unsigned short* W2h, const unsigned short* W2l, const void* b2, const void* a2p,
    const unsigned short* W3h, const unsigned short* W3l, const void* b3, const void* a3p,
    const unsigned short* W4h, const unsigned short* W4l, const void* b4,
    const void* encb, void* out) {
    // union: conv staging {se16/si16 bf16 + kef/kif f32, 43.6 KB} then MLP
    // {Ahi+Alo, 64 KB} — sequential phases. + Sc[2][64][16] (8 KB).
    __shared__ __align__(16) unsigned char smem[65536];
    __shared__ __align__(16) float Sc[2 * 64 * 16];   // [arr][row][s]
    __shared__ int sfl;

    unsigned short* se16 = (unsigned short*)smem;        // [263*17] bf16
    unsigned short* si16 = se16 + 4472;                  // 16B-aligned
    float* kef = (float*)(smem + 17888);                 // [16][201] f32
    float* kif = kef + 16 * 201;                         // end byte 43616

    int tid = threadIdx.x;
    int t0 = blockIdx.x * 64;

    // stage conv windows as bf16 (counts <=255 exact) + kernel coeffs
    for (int idx = tid; idx < 263 * 4; idx += 256) {
        int r = idx >> 2, wi = idx & 3;
        int t = t0 - 199 + r;
        unsigned int ve = 0, vi = 0;
        if (t >= 0 && t < T_DATA) {
            ve = ((const unsigned int*)in_e)[t * 4 + wi];
            vi = ((const unsigned int*)in_i)[t * 4 + wi];
        }
        #pragma unroll
        for (int b = 0; b < 4; b++) {
            se16[r * 17 + wi * 4 + b] = f2bf((float)((ve >> (8 * b)) & 0xFF));
            si16[r * 17 + wi * 4 + b] = f2bf((float)((vi >> (8 * b)) & 0xFF));
        }
    }
    for (int idx = tid; idx < 3200; idx += 256) {
        int s2 = idx / 200, j = idx - s2 * 200;
        kef[s2 * 201 + j] = ker_e[idx];
        kif[s2 * 201 + j] = ker_i[idx];
    }
    int f = detect_bf(Se, &sfl);   // its double-sync covers the staging above

    {   // conv: e/i split, 8 rows/thread, 2 LDS reads/j (r10 form, unroll 2)
        int arr = tid >> 7;                   // 0: e-array, 1: i-array
        int g8 = ((tid >> 4) & 7) * 8;        // base output row (0..56)
        int s  = tid & 15;                    // subunit
        const unsigned short* src = arr ? si16 : se16;
        const float* kf = arr ? kif : kef;
        float w[8], acc8[8];
        #pragma unroll
        for (int i = 0; i < 8; i++) {
            w[i] = bf2f(src[(g8 + i + 199) * 17 + s]);
            acc8[i] = 0.f;
        }
        #pragma unroll 2
        for (int j = 0; j < 200; j++) {
            float kj = kf[s * 201 + j];
            #pragma unroll
            for (int i = 0; i < 8; i++) acc8[i] += w[i] * kj;
            int lr = g8 + 198 - j; lr = lr < 0 ? 0 : lr;   // j=199 value unused
            float nv = bf2f(src[lr * 17 + s]);
            #pragma unroll
            for (int i = 7; i > 0; i--) w[i] = w[i - 1];
            w[0] = nv;
        }
        #pragma unroll
        for (int i = 0; i < 8; i++)
            Sc[arr * 1024 + (g8 + i) * 16 + s] = acc8[i];
    }
    __syncthreads();   // Sc ready; conv staging dead -> union free for Ahi/Alo

    unsigned short* Ahi = (unsigned short*)smem;
    unsigned short* Alo = Ahi + 64 * 256;
    if (f)
        mlp_body<true>(V, W1h, W1l, b1, a1p, W2h, W2l, b2, a2p, W3h, W3l, b3, a3p,
                       W4h, W4l, b4, encb, Sc, out, Ahi, Alo);
    else
        mlp_body<false>(V, W1h, W1l, b1, a1p, W2h, W2l, b2, a2p, W3h, W3l, b3, a3p,
                        W4h, W4l, b4, encb, Sc, out, Ahi, Alo);
}

extern "C" void kernel_launch(void* const* d_in, const int* in_sizes, int n_in,
                              void* d_out, int out_size, void* d_ws, size_t ws_size,
                              hipStream_t stream) {
    const void* V    = d_in[0];
    const void* Se   = d_in[1];
    const void* Si   = d_in[2];
    const void* Ce   = d_in[3];
    const void* Ci   = d_in[4];
    const void* Ksyn = d_in[5];
    const void* tau  = d_in[6];
    const void* dly  = d_in[7];
    const void* encb = d_in[8];
    const void* W1   = d_in[9];
    const void* b1   = d_in[10];
    const void* a1   = d_in[11];
    const void* W2   = d_in[12];
    const void* b2   = d_in[13];
    const void* a2   = d_in[14];
    const void* W3   = d_in[15];
    const void* b3   = d_in[16];
    const void* a3   = d_in[17];
    const void* W4   = d_in[18];
    const void* b4   = d_in[19];

    char* w = (char*)d_ws;
    float* ker_e = (float*)(w + OFF_KERE);
    float* ker_i = (float*)(w + OFF_KERI);
    unsigned char* sh_e = (unsigned char*)(w + OFF_SHE);
    unsigned char* sh_i = (unsigned char*)(w + OFF_SHI);
    unsigned short* W1h = (unsigned short*)(w + OFF_W1H);
    unsigned short* W1l = (unsigned short*)(w + OFF_W1L);
    unsigned short* W2h = (unsigned short*)(w + OFF_W2H);
    unsigned short* W2l = (unsigned short*)(w + OFF_W2L);
    unsigned short* W3h = (unsigned short*)(w + OFF_W3H);
    unsigned short* W3l = (unsigned short*)(w + OFF_W3L);
    unsigned short* W4h = (unsigned short*)(w + OFF_W4H);
    unsigned short* W4l = (unsigned short*)(w + OFF_W4L);
    unsigned char* in_e = (unsigned char*)(w + OFF_INE);
    unsigned char* in_i = (unsigned char*)(w + OFF_INI);

    k_tables<<<35, 256, 0, stream>>>(Se, Ksyn, tau, dly, Ce, Ci,
                                     ker_e, ker_i, sh_e, sh_i);
    k_spikes<<<5000, 256, 0, stream>>>(Se, Si, sh_e, sh_i, W1, W2, W3, W4,
                                       in_e, in_i,
                                       W1h, W1l, W2h, W2l, W3h, W3l, W4h, W4l);
    k_convmlp<<<313, 256, 0, stream>>>(Se, V, in_e, in_i, ker_e, ker_i,
                                       W1h, W1l, b1, a1, W2h, W2l, b2, a2,
                                       W3h, W3l, b3, a3, W4h, W4l, b4,
                                       encb, d_out);
}